// Round 5
// baseline (6952.711 us; speedup 1.0000x reference)
//
#include <hip/hip_runtime.h>
#include <hip/hip_fp16.h>

typedef _Float16 f16;
typedef __attribute__((ext_vector_type(8))) _Float16 f16x8;
typedef __attribute__((ext_vector_type(16))) float f32x16;

#define GLL(src, dst) __builtin_amdgcn_global_load_lds( \
    (const __attribute__((address_space(1))) void*)(src), \
    (__attribute__((address_space(3))) void*)(dst), 16, 0, 0)

// Fragment-order storage: tensor[r, k] lives at chunk (r>>5)*nkb + (k>>4), a
// 512-elem (1KB) chunk holding lane*8+e -> (r = base + (lane&31),
// k = kchunk*16 + (lane>>5)*8 + e).  This IS the mfma_32x32x16 A/B fragment
// layout (verified R3/R4: frag row = lane&31, k = (lane>>5)*8+e), so a wave
// fetches one fragment with ONE contiguous 1KB global_load_dwordx4.
__device__ __forceinline__ size_t foff(int r, int k, int nkb) {
    return ((size_t)((r >> 5) * nkb + (k >> 4)) << 9)
         + (size_t)(((((k >> 3) & 1)) << 8) + ((r & 31) << 3) + (k & 7));
}

// ---------------------------------------------------------------------------
// Register GEMM core: block = 128 threads = 2 waves; wave wv computes a
// 64x64 output tile (rows wv*64, all 64 block cols) as acc[2][2] 32x32 tiles.
// A-fragments: DIRECT global->register (per-wave-private rows, frag-order
// storage, no LDS). B-fragments: shared by both waves -> staged to LDS via
// global_load_lds (global image == LDS image, linear), read as contiguous
// ds_read_b128.  Double-buffered (buf 4KB x2), counted vmcnt: per iter the
// issue group = {2 GLL + 4 A-loads} = 6; steady wait vmcnt(6) keeps next
// group in flight.  Groups are separated by asm fences, so drain order is
// robust to within-iter reordering.  Raw s_barrier (never __syncthreads).
// ---------------------------------------------------------------------------
__device__ __forceinline__ void rgemm(
    const f16* __restrict__ pA0, const f16* __restrict__ pA1,
    const f16* __restrict__ pB0, const f16* __restrict__ pB1,
    f16* sB, int wv, int lane, int n, f32x16 acc[2][2])
{
    #pragma unroll
    for (int mt = 0; mt < 2; ++mt)
      #pragma unroll
      for (int nt = 0; nt < 2; ++nt)
        #pragma unroll
        for (int e = 0; e < 16; ++e)
          acc[mt][nt][e] = 0.f;

    f16x8 X[2][2], Y[2][2];
    auto LA = [&](f16x8 (&R)[2][2], int t) {    // 4 loads
        size_t o = (size_t)t * 1024;
        R[0][0] = *(const f16x8*)(pA0 + o);
        R[0][1] = *(const f16x8*)(pA0 + o + 512);
        R[1][0] = *(const f16x8*)(pA1 + o);
        R[1][1] = *(const f16x8*)(pA1 + o + 512);
    };
    auto BG = [&](int buf, int t) {             // 2 GLL (wave wv stages kk=wv)
        size_t o = (size_t)t * 1024;
        GLL(pB0 + o, sB + buf * 2048 + wv * 512);
        GLL(pB1 + o, sB + buf * 2048 + 1024 + wv * 512);
    };
    auto STEP = [&](f16x8 (&R)[2][2], int buf, int t, bool last) {
        if (last) asm volatile("s_waitcnt vmcnt(0)" ::: "memory");
        else      asm volatile("s_waitcnt vmcnt(6)" ::: "memory");
        __builtin_amdgcn_sched_barrier(0);
        __builtin_amdgcn_s_barrier();           // B(t) fully in LDS
        __builtin_amdgcn_sched_barrier(0);
        f16x8 bf[2][2];
        const f16* bb = sB + buf * 2048 + lane * 8;
        #pragma unroll
        for (int nt = 0; nt < 2; ++nt)
          #pragma unroll
          for (int kk = 0; kk < 2; ++kk)
            bf[nt][kk] = *(const f16x8*)(bb + nt * 1024 + kk * 512);
        asm volatile("s_waitcnt lgkmcnt(0)" ::: "memory");
        __builtin_amdgcn_sched_barrier(0);      // rule #18 fence
        __builtin_amdgcn_s_barrier();           // all waves done reading buf
        __builtin_amdgcn_sched_barrier(0);
        if (t + 2 < n) BG(buf, t + 2);
        __builtin_amdgcn_s_setprio(1);
        #pragma unroll
        for (int kk = 0; kk < 2; ++kk)
          #pragma unroll
          for (int mt = 0; mt < 2; ++mt)
            #pragma unroll
            for (int nt = 0; nt < 2; ++nt)
              acc[mt][nt] = __builtin_amdgcn_mfma_f32_32x32x16_f16(
                  R[mt][kk], bf[nt][kk], acc[mt][nt], 0, 0, 0);
        __builtin_amdgcn_s_setprio(0);
        if (t + 2 < n) LA(R, t + 2);
    };

    __builtin_amdgcn_sched_barrier(0);
    BG(0, 0); LA(X, 0);
    __builtin_amdgcn_sched_barrier(0);          // keep group(0) before group(1)
    BG(1, 1); LA(Y, 1);
    __builtin_amdgcn_sched_barrier(0);
    for (int t = 0; t < n; t += 2) {            // n even (K in {128, 2048})
        STEP(X, 0, t, false);
        STEP(Y, 1, t + 1, t + 2 >= n);
    }
}

#define PICKV(ii) ((ii) == 0 ? w0[e] : (ii) == 1 ? w1[e] : (ii) == 2 ? w2[e] : w3[e])

// ---------------------------------------------------------------------------
// Recurrent step: gates = A @ W^T + bias ; cell ; h out (frag-order), c (f32).
// W stored gate-interleaved: row rho = hid*4 + gate, so a lane's acc column
// is one gate of one hid; the 4 gates of a hid live in one lane-quad ->
// 3x shfl_xor gather, no LDS exchange.  Block = 128 batch x 16 hid.
// ---------------------------------------------------------------------------
__global__ __launch_bounds__(128) void k_step(
    const f16* __restrict__ Af, int nkb,
    const f16* __restrict__ Bf,
    const float* __restrict__ bias,
    float* __restrict__ Cst,
    f16* __restrict__ Hout)
{
    __shared__ alignas(16) f16 sB[4096];
    const int P = blockIdx.x;
    const int L = (P & 7) * ((int)gridDim.x >> 3) + (P >> 3);  // XCD swizzle
    const int cg = L >> 2, rg = L & 3;
    const int tid = threadIdx.x;
    const int wv = tid >> 6, lane = tid & 63;
    const int l31 = lane & 31, hi = lane >> 5;
    const int mb = rg * 4 + wv * 2;
    const int nb = cg * 2;
    const f16* pA0 = Af + ((size_t)mb * nkb) * 512 + lane * 8;
    const f16* pA1 = pA0 + (size_t)nkb * 512;
    const f16* pB0 = Bf + ((size_t)nb * nkb + wv) * 512 + (size_t)lane * 8;
    const f16* pB1 = pB0 + (size_t)nkb * 512;
    f32x16 acc[2][2];
    rgemm(pA0, pA1, pB0, pB1, sB, wv, lane, nkb >> 1, acc);

    const int g = l31 & 3;                      // this lane's gate
    #pragma unroll
    for (int nt = 0; nt < 2; ++nt) {
        const int hid = cg * 16 + nt * 8 + (l31 >> 2);
        const float bown = bias[(g << 11) + hid];
        #pragma unroll
        for (int mt = 0; mt < 2; ++mt) {
            float w0[16], w1[16], w2[16], w3[16];
            #pragma unroll
            for (int e = 0; e < 16; ++e) {      // own-gate nonlinearity first
                float x = acc[mt][nt][e] + bown;
                float xx = (g == 2) ? 2.f * x : x;
                float s = 1.f / (1.f + __expf(-xx));
                w0[e] = (g == 2) ? 2.f * s - 1.f : s;   // tanh = 2*sig(2x)-1
            }
            #pragma unroll
            for (int e = 0; e < 16; ++e) {      // quad gather (xor 1,2,3)
                w1[e] = __shfl_xor(w0[e], 1);
                w2[e] = __shfl_xor(w0[e], 2);
                w3[e] = __shfl_xor(w0[e], 3);
            }
            const int rowb = rg * 128 + wv * 64 + mt * 32 + 4 * hi;
            #pragma unroll
            for (int eg = 0; eg < 4; ++eg) {
                if (g == eg) {                  // static indices inside
                    #pragma unroll
                    for (int q = 0; q < 4; ++q) {
                        const int e = eg * 4 + q;
                        const float iv = PICKV(eg ^ 0);
                        const float fv = PICKV(eg ^ 1);
                        const float gv = PICKV(eg ^ 2);
                        const float ov = PICKV(eg ^ 3);
                        const int row = rowb + q + 8 * eg;
                        const size_t cidx = (size_t)row * 2048 + hid;
                        const float c = fv * Cst[cidx] + iv * gv;
                        Cst[cidx] = c;
                        Hout[foff(row, hid, 128)] = (f16)(ov * tanhf(c));
                    }
                }
            }
        }
    }
}

// out[b, t0+slot, d] = H @ W_out^T + b_out over M = depth*512 rows
__global__ __launch_bounds__(128) void k_out(
    const f16* __restrict__ Hbase, const f16* __restrict__ Bf,
    const float* __restrict__ bout, float* __restrict__ out,
    int t0, int rgshift)
{
    __shared__ alignas(16) f16 sB[4096];
    const int P = blockIdx.x;
    const int L = (P & 7) * ((int)gridDim.x >> 3) + (P >> 3);
    const int cg = L >> rgshift;                // 0..1
    const int rg = L & ((1 << rgshift) - 1);
    const int tid = threadIdx.x;
    const int wv = tid >> 6, lane = tid & 63;
    const int l31 = lane & 31, hi = lane >> 5;
    const int mbg = rg * 4 + wv * 2;            // 32-row units over depth*512
    const int slot = mbg >> 4, mloc = mbg & 15; // mloc even -> no slot cross
    const f16* pA0 = Hbase + (size_t)slot * 1048576
                   + ((size_t)mloc * 128) * 512 + lane * 8;
    const f16* pA1 = pA0 + 128 * 512;
    const int nb = cg * 2;
    const f16* pB0 = Bf + ((size_t)nb * 128 + wv) * 512 + (size_t)lane * 8;
    const f16* pB1 = pB0 + (size_t)128 * 512;
    f32x16 acc[2][2];
    rgemm(pA0, pA1, pB0, pB1, sB, wv, lane, 64, acc);

    #pragma unroll
    for (int nt = 0; nt < 2; ++nt) {
        const int d = cg * 64 + nt * 32 + l31;
        const float bo = bout[d];
        #pragma unroll
        for (int mt = 0; mt < 2; ++mt)
          #pragma unroll
          for (int e = 0; e < 16; ++e) {
            const int m = rg * 128 + wv * 64 + mt * 32
                        + (e & 3) + 8 * (e >> 2) + 4 * hi;
            out[(size_t)(m & 511) * 16384 + (size_t)(t0 + (m >> 9)) * 128 + d]
                = acc[mt][nt][e] + bo;
          }
    }
}

// Wc[r,k] = Whh[r,k] + Wih[r,:] @ Wout[:,k]; writes gate-interleaved frag-order
__global__ __launch_bounds__(128) void k_wcomb(
    const f16* __restrict__ Af,   // Wihaf  (8192x128 A-frag order, nkb=8)
    const f16* __restrict__ Bf,   // WoutTf (2048x128 B-frag order, nkb=8)
    const float* __restrict__ Whh, f16* __restrict__ Wf)
{
    __shared__ alignas(16) f16 sB[4096];
    const int P = blockIdx.x;
    const int L = (P & 7) * ((int)gridDim.x >> 3) + (P >> 3);
    const int cg = L >> 6, rg = L & 63;
    const int tid = threadIdx.x;
    const int wv = tid >> 6, lane = tid & 63;
    const int l31 = lane & 31, hi = lane >> 5;
    const int mb = rg * 4 + wv * 2, nb = cg * 2;
    const f16* pA0 = Af + ((size_t)mb * 8) * 512 + lane * 8;
    const f16* pA1 = pA0 + 8 * 512;
    const f16* pB0 = Bf + ((size_t)nb * 8 + wv) * 512 + (size_t)lane * 8;
    const f16* pB1 = pB0 + 8 * 512;
    f32x16 acc[2][2];
    rgemm(pA0, pA1, pB0, pB1, sB, wv, lane, 4, acc);

    #pragma unroll
    for (int nt = 0; nt < 2; ++nt) {
        const int kc = cg * 64 + nt * 32 + l31;
        #pragma unroll
        for (int mt = 0; mt < 2; ++mt)
          #pragma unroll
          for (int e = 0; e < 16; ++e) {
            const int r = rg * 128 + wv * 64 + mt * 32
                        + (e & 3) + 8 * (e >> 2) + 4 * hi;
            const float v = acc[mt][nt][e] + Whh[(size_t)r * 2048 + kc];
            const int rho = ((r & 2047) << 2) | (r >> 11);  // hid*4 + gate
            Wf[foff(rho, kc, 128)] = (f16)v;
          }
    }
}

// ---------------- prep kernels (once per launch, elementwise) ---------------

__global__ void k_x0f(const float* __restrict__ tgt, f16* __restrict__ x0f)
{   // x0 in A-frag order, nkb=8
    int i = blockIdx.x * 256 + threadIdx.x;     // 65536
    int b = i >> 7, k = i & 127;
    x0f[foff(b, k, 8)] = (f16)tgt[(size_t)b * 16384 + k];
}

__global__ void k_wihf(const float* __restrict__ Wih, f16* __restrict__ Wihf)
{   // W_ih in B-frag order, gate-interleaved rows, nkb=8
    int i = blockIdx.x * 256 + threadIdx.x;     // 1048576
    int rho = i >> 7, k = i & 127;
    int gate = rho & 3, hid = rho >> 2;
    Wihf[foff(rho, k, 8)] = (f16)Wih[((size_t)gate * 2048 + hid) * 128 + k];
}

__global__ void k_wihaf(const float* __restrict__ Wih, f16* __restrict__ Wihaf)
{   // W_ih in A-frag order (for k_wcomb), nkb=8
    int i = blockIdx.x * 256 + threadIdx.x;     // 1048576
    int r = i >> 7, k = i & 127;
    Wihaf[foff(r, k, 8)] = (f16)Wih[(size_t)r * 128 + k];
}

__global__ void k_woutTf(const float* __restrict__ Wout, f16* __restrict__ WoutTf)
{   // Wout^T (2048x128) in B-frag order (for k_wcomb), nkb=8
    int i = blockIdx.x * 256 + threadIdx.x;     // 262144
    int d = i >> 11, n = i & 2047;
    WoutTf[foff(n, d, 8)] = (f16)Wout[(size_t)d * 2048 + n];
}

__global__ void k_woutf(const float* __restrict__ Wout, f16* __restrict__ Woutf)
{   // Wout (128x2048) in B-frag order (for k_out), nkb=128
    int i = blockIdx.x * 256 + threadIdx.x;     // 262144
    int d = i >> 11, k = i & 2047;
    Woutf[foff(d, k, 128)] = (f16)Wout[(size_t)d * 2048 + k];
}

__global__ void k_bias(const float* __restrict__ bih, const float* __restrict__ bhh,
                       const float* __restrict__ Wih, const float* __restrict__ bout,
                       float* __restrict__ b0, float* __restrict__ bp)
{
    int r = blockIdx.x * 256 + threadIdx.x;
    if (r >= 8192) return;
    float s = bih[r] + bhh[r];
    float a = 0.f;
    for (int d = 0; d < 128; ++d) a += Wih[(size_t)r * 128 + d] * bout[d];
    b0[r] = s;        // step-0 bias
    bp[r] = s + a;    // recurrent bias (absorbs W_ih @ b_out)
}

// ---------------------------------------------------------------------------

extern "C" void kernel_launch(void* const* d_in, const int* in_sizes, int n_in,
                              void* d_out, int out_size, void* d_ws, size_t ws_size,
                              hipStream_t stream)
{
    const float* tgt  = (const float*)d_in[0];
    const float* Wih  = (const float*)d_in[1];
    const float* Whh  = (const float*)d_in[2];
    const float* bih  = (const float*)d_in[3];
    const float* bhh  = (const float*)d_in[4];
    const float* Wout = (const float*)d_in[5];
    const float* bout = (const float*)d_in[6];
    float* out = (float*)d_out;

    char* ws = (char*)d_ws;
    size_t off = 0;
    auto alloc = [&](size_t bytes) -> void* {
        void* p = ws + off;
        off += (bytes + 255) & ~(size_t)255;
        return p;
    };
    f16*   Wf     = (f16*)alloc((size_t)8192 * 2048 * 2);  // W' frag-order
    f16*   Wihf   = (f16*)alloc((size_t)8192 * 128 * 2);
    f16*   Wihaf  = (f16*)alloc((size_t)8192 * 128 * 2);
    f16*   WoutTf = (f16*)alloc((size_t)2048 * 128 * 2);
    f16*   Woutf  = (f16*)alloc((size_t)128 * 2048 * 2);
    f16*   x0f    = (f16*)alloc((size_t)512 * 128 * 2);
    float* b0     = (float*)alloc(8192 * 4);
    float* bp     = (float*)alloc(8192 * 4);
    float* Cst    = (float*)alloc((size_t)512 * 2048 * 4);

    const size_t slotsz = (size_t)512 * 2048;  // elements per h snapshot
    int depth = 0;
    const int cands[7] = {128, 64, 32, 16, 8, 4, 2};
    for (int i = 0; i < 7; ++i)
        if (off + (size_t)cands[i] * slotsz * 2 <= ws_size) { depth = cands[i]; break; }
    if (depth == 0) return;
    f16* Hbuf = (f16*)alloc((size_t)depth * slotsz * 2);
    const int rgshift = __builtin_ctz((unsigned)(depth * 4));

    hipMemsetAsync(Cst, 0, (size_t)512 * 2048 * 4, stream);
    k_x0f   <<<dim3(256),  dim3(256), 0, stream>>>(tgt, x0f);
    k_wihf  <<<dim3(4096), dim3(256), 0, stream>>>(Wih, Wihf);
    k_wihaf <<<dim3(4096), dim3(256), 0, stream>>>(Wih, Wihaf);
    k_woutTf<<<dim3(1024), dim3(256), 0, stream>>>(Wout, WoutTf);
    k_woutf <<<dim3(1024), dim3(256), 0, stream>>>(Wout, Woutf);
    k_bias  <<<dim3(32),   dim3(256), 0, stream>>>(bih, bhh, Wih, bout, b0, bp);
    k_wcomb <<<dim3(2048), dim3(128), 0, stream>>>(Wihaf, WoutTf, Whh, Wf);

    // step 0: gates = x0 @ W_ih^T + (b_ih+b_hh)  -> h^1 in slot 0
    k_step<<<dim3(512), dim3(128), 0, stream>>>(x0f, 8, Wihf, b0, Cst, Hbuf);
    // steps 1..127: gates = h @ W'^T + b'
    for (int s = 1; s < 128; ++s) {
        if ((s % depth) == 0)
            k_out<<<dim3(8 * depth), dim3(128), 0, stream>>>(
                Hbuf, Woutf, bout, out, s - depth, rgshift);
        k_step<<<dim3(512), dim3(128), 0, stream>>>(
            Hbuf + (size_t)((s - 1) % depth) * slotsz, 128, Wf, bp,
            Cst, Hbuf + (size_t)(s % depth) * slotsz);
    }
    k_out<<<dim3(8 * depth), dim3(128), 0, stream>>>(
        Hbuf, Woutf, bout, out, 128 - depth, rgshift);
}

// Round 6
// 4538.225 us; speedup vs baseline: 1.5320x; 1.5320x over previous
//
#include <hip/hip_runtime.h>
#include <hip/hip_fp16.h>

typedef _Float16 f16;
typedef __attribute__((ext_vector_type(8))) _Float16 f16x8;
typedef __attribute__((ext_vector_type(16))) float f32x16;

#define GLL(src, dst) __builtin_amdgcn_global_load_lds( \
    (const __attribute__((address_space(1))) void*)(src), \
    (__attribute__((address_space(3))) void*)(dst), 16, 0, 0)

// Fragment-order storage (verified R5, passed): tensor[r,k] -> chunk
// (r>>5)*nkb + (k>>4); 512-elem 1KB chunk holds lane*8+e with
// r = base + (lane&31), k = kchunk*16 + (lane>>5)*8 + e.  One chunk == one
// mfma_32x32x16 A/B fragment for a 32-row block, loaded as a single
// contiguous 1KB wave read.
__device__ __forceinline__ size_t foff(int r, int k, int nkb) {
    return ((size_t)((r >> 5) * nkb + (k >> 4)) << 9)
         + (size_t)(((((k >> 3) & 1)) << 8) + ((r & 31) << 3) + (k & 7));
}

// ---------------------------------------------------------------------------
// Register GEMM core: block = 256 threads = 4 waves, each wave owns a
// PRIVATE 32-row stripe and ALL 64 block cols (wave-tile 32x64, acc[2]).
// A: direct global->register (frag-order, per-wave-private, no LDS).
// B: shared by all 4 waves -> staged to LDS via global_load_lds (global
// image == LDS image, linear), read as contiguous ds_read_b128.
// Double-buffered (2 x 8KB), counted vmcnt: issue group per K-64 iter =
// {2 GLL + 4 A-loads} = 6/thread; steady wait vmcnt(6) keeps the next
// group fully in flight.  Grid 512 x 256thr = 2 blocks/CU = 2 waves/SIMD:
// latency hiding comes from 4 independent wave contexts per SIMD
// (R1-proven concurrency; R3/R5's 1 wave/SIMD was the latency cliff).
// ---------------------------------------------------------------------------
__device__ __forceinline__ void rgemm(
    const f16* __restrict__ pA,              // wave A stripe base + lane*8
    const f16* __restrict__ pB0, const f16* __restrict__ pB1,
    f16* sB, int wv, int lane, int n, f32x16 acc[2])
{
    #pragma unroll
    for (int nt = 0; nt < 2; ++nt)
      #pragma unroll
      for (int e = 0; e < 16; ++e)
        acc[nt][e] = 0.f;

    // wave's staging assignment: col-block c = wv>>1, k-chunk pair (wv&1)
    const f16* pBs = (wv >> 1) ? pB1 : pB0;
    const int jb = (wv & 1) * 2;
    f16* dst0 = sB + (wv >> 1) * 2048 + jb * 512;   // + buf*4096

    f16x8 X[4], Y[4];
    auto LA = [&](f16x8 (&R)[4], int t) {           // 4 A-frag loads (K-64)
        size_t o = (size_t)t * 2048;
        R[0] = *(const f16x8*)(pA + o);
        R[1] = *(const f16x8*)(pA + o + 512);
        R[2] = *(const f16x8*)(pA + o + 1024);
        R[3] = *(const f16x8*)(pA + o + 1536);
    };
    auto BG = [&](int buf, int t) {                 // 2 GLL per wave
        size_t o = (size_t)t * 2048 + (size_t)jb * 512;
        GLL(pBs + o,       dst0 + buf * 4096);
        GLL(pBs + o + 512, dst0 + buf * 4096 + 512);
    };
    auto STEP = [&](f16x8 (&R)[4], int buf, int t, bool last) {
        if (last) asm volatile("s_waitcnt vmcnt(0)" ::: "memory");
        else      asm volatile("s_waitcnt vmcnt(6)" ::: "memory");
        __builtin_amdgcn_sched_barrier(0);
        __builtin_amdgcn_s_barrier();               // B(t) fully in LDS
        __builtin_amdgcn_sched_barrier(0);
        f16x8 bf[2][4];
        const f16* bb = sB + buf * 4096 + lane * 8;
        #pragma unroll
        for (int nt = 0; nt < 2; ++nt)
          #pragma unroll
          for (int kk = 0; kk < 4; ++kk)
            bf[nt][kk] = *(const f16x8*)(bb + nt * 2048 + kk * 512);
        asm volatile("s_waitcnt lgkmcnt(0)" ::: "memory");
        __builtin_amdgcn_sched_barrier(0);          // rule #18 fence
        __builtin_amdgcn_s_barrier();               // all waves done reading
        __builtin_amdgcn_sched_barrier(0);
        if (t + 2 < n) BG(buf, t + 2);              // async refill
        __builtin_amdgcn_s_setprio(1);
        #pragma unroll
        for (int kk = 0; kk < 4; ++kk)
          #pragma unroll
          for (int nt = 0; nt < 2; ++nt)
            acc[nt] = __builtin_amdgcn_mfma_f32_32x32x16_f16(
                R[kk], bf[nt][kk], acc[nt], 0, 0, 0);
        __builtin_amdgcn_s_setprio(0);
        if (t + 2 < n) LA(R, t + 2);                // WAR on R keeps order
    };

    __builtin_amdgcn_sched_barrier(0);
    BG(0, 0); LA(X, 0);
    __builtin_amdgcn_sched_barrier(0);              // group(0) before group(1)
    BG(1, 1); LA(Y, 1);
    __builtin_amdgcn_sched_barrier(0);
    for (int t = 0; t < n; t += 2) {                // n even (K in {128,2048})
        STEP(X, 0, t, false);
        STEP(Y, 1, t + 1, t + 2 >= n);
    }
}

#define PICKV(ii) ((ii) == 0 ? w0[e] : (ii) == 1 ? w1[e] : (ii) == 2 ? w2[e] : w3[e])

// ---------------------------------------------------------------------------
// Recurrent step: gates = A @ W^T + bias ; cell ; h out (frag-order), c f32.
// W gate-interleaved (rho = hid*4 + gate): a lane-quad holds the 4 gates of
// one hid -> 3x shfl_xor gather, no LDS exchange (verified R5).
// Block = 128 batch rows x 64 gate-cols; grid 512 = 128 cg x 4 rg.
// ---------------------------------------------------------------------------
__global__ __launch_bounds__(256, 2) void k_step(
    const f16* __restrict__ Af, int nkb,
    const f16* __restrict__ Bf,
    const float* __restrict__ bias,
    float* __restrict__ Cst,
    f16* __restrict__ Hout)
{
    __shared__ alignas(16) f16 sB[8192];            // 2 x 8KB
    const int P = blockIdx.x;
    const int L = (P & 7) * ((int)gridDim.x >> 3) + (P >> 3);  // XCD swizzle
    const int cg = L >> 2, rg = L & 3;              // cg-major per XCD:
    const int tid = threadIdx.x;                    // W' panel L2-resident
    const int wv = tid >> 6, lane = tid & 63;
    const int l31 = lane & 31, hi = lane >> 5;
    const int mb = rg * 4 + wv;                     // 32-row A stripe
    const f16* pA  = Af + ((size_t)mb * nkb) * 512 + lane * 8;
    const f16* pB0 = Bf + ((size_t)(cg * 2) * nkb) * 512 + lane * 8;
    const f16* pB1 = pB0 + (size_t)nkb * 512;
    f32x16 acc[2];
    rgemm(pA, pB0, pB1, sB, wv, lane, nkb >> 2, acc);

    const int g = l31 & 3;                          // this lane's gate
    #pragma unroll
    for (int nt = 0; nt < 2; ++nt) {
        const int hid = cg * 16 + nt * 8 + (l31 >> 2);
        const float bown = bias[(g << 11) + hid];
        float w0[16], w1[16], w2[16], w3[16];
        #pragma unroll
        for (int e = 0; e < 16; ++e) {              // own-gate nonlinearity
            float x = acc[nt][e] + bown;
            float xx = (g == 2) ? 2.f * x : x;
            float s = 1.f / (1.f + __expf(-xx));
            w0[e] = (g == 2) ? 2.f * s - 1.f : s;   // tanh = 2*sig(2x)-1
        }
        #pragma unroll
        for (int e = 0; e < 16; ++e) {              // quad gather
            w1[e] = __shfl_xor(w0[e], 1);
            w2[e] = __shfl_xor(w0[e], 2);
            w3[e] = __shfl_xor(w0[e], 3);
        }
        const int rowb = rg * 128 + wv * 32 + 4 * hi;
        #pragma unroll
        for (int eg = 0; eg < 4; ++eg) {
            if (g == eg) {                          // static indices inside
                #pragma unroll
                for (int q = 0; q < 4; ++q) {
                    const int e = eg * 4 + q;
                    const float iv = PICKV(eg ^ 0);
                    const float fv = PICKV(eg ^ 1);
                    const float gv = PICKV(eg ^ 2);
                    const float ov = PICKV(eg ^ 3);
                    const int row = rowb + q + 8 * eg;
                    const size_t cidx = (size_t)row * 2048 + hid;
                    const float c = fv * Cst[cidx] + iv * gv;
                    Cst[cidx] = c;
                    Hout[foff(row, hid, 128)] = (f16)(ov * tanhf(c));
                }
            }
        }
    }
}

// out[b, t0+slot, d] = H @ W_out^T + b_out over M = depth*512 rows
__global__ __launch_bounds__(256, 2) void k_out(
    const f16* __restrict__ Hbase, const f16* __restrict__ Bf,
    const float* __restrict__ bout, float* __restrict__ out,
    int t0, int rgshift)
{
    __shared__ alignas(16) f16 sB[8192];
    const int P = blockIdx.x;
    const int L = (P & 7) * ((int)gridDim.x >> 3) + (P >> 3);
    const int cg = L >> rgshift;                    // 0..1
    const int rg = L & ((1 << rgshift) - 1);        // 0..depth*4-1
    const int tid = threadIdx.x;
    const int wv = tid >> 6, lane = tid & 63;
    const int l31 = lane & 31, hi = lane >> 5;
    const int m0 = rg * 128 + wv * 32;              // wave row stripe
    const int slot = m0 >> 9, mloc32 = (m0 & 511) >> 5;
    const f16* pA  = Hbase + (size_t)slot * 1048576
                   + ((size_t)mloc32 * 128) * 512 + lane * 8;
    const f16* pB0 = Bf + ((size_t)(cg * 2) * 128) * 512 + lane * 8;
    const f16* pB1 = pB0 + (size_t)128 * 512;
    f32x16 acc[2];
    rgemm(pA, pB0, pB1, sB, wv, lane, 32, acc);

    #pragma unroll
    for (int nt = 0; nt < 2; ++nt) {
        const int d = cg * 64 + nt * 32 + l31;
        const float bo = bout[d];
        #pragma unroll
        for (int e = 0; e < 16; ++e) {
            const int m = m0 + (e & 3) + 8 * (e >> 2) + 4 * hi;
            out[(size_t)(m & 511) * 16384 + (size_t)(t0 + (m >> 9)) * 128 + d]
                = acc[nt][e] + bo;
        }
    }
}

// Wc[r,k] = Whh[r,k] + Wih[r,:] @ Wout[:,k]; writes gate-interleaved frag-order
__global__ __launch_bounds__(256, 2) void k_wcomb(
    const f16* __restrict__ Af,   // Wihaf  (8192x128 A-frag order, nkb=8)
    const f16* __restrict__ Bf,   // WoutTf (2048x128 B-frag order, nkb=8)
    const float* __restrict__ Whh, f16* __restrict__ Wf)
{
    __shared__ alignas(16) f16 sB[8192];
    const int P = blockIdx.x;
    const int L = (P & 7) * ((int)gridDim.x >> 3) + (P >> 3);
    const int cg = L >> 6, rg = L & 63;             // 32 cg x 64 rg
    const int tid = threadIdx.x;
    const int wv = tid >> 6, lane = tid & 63;
    const int l31 = lane & 31, hi = lane >> 5;
    const int mb = rg * 4 + wv;
    const f16* pA  = Af + ((size_t)mb * 8) * 512 + lane * 8;
    const f16* pB0 = Bf + ((size_t)(cg * 2) * 8) * 512 + lane * 8;
    const f16* pB1 = pB0 + (size_t)8 * 512;
    f32x16 acc[2];
    rgemm(pA, pB0, pB1, sB, wv, lane, 2, acc);

    #pragma unroll
    for (int nt = 0; nt < 2; ++nt) {
        const int kc = cg * 64 + nt * 32 + l31;
        #pragma unroll
        for (int e = 0; e < 16; ++e) {
            const int r = rg * 128 + wv * 32 + (e & 3) + 8 * (e >> 2) + 4 * hi;
            const float v = acc[nt][e] + Whh[(size_t)r * 2048 + kc];
            const int rho = ((r & 2047) << 2) | (r >> 11);  // hid*4 + gate
            Wf[foff(rho, kc, 128)] = (f16)v;
        }
    }
}

// ---------------- prep kernels (once per launch, elementwise) ---------------

__global__ void k_x0f(const float* __restrict__ tgt, f16* __restrict__ x0f)
{   // x0 in A-frag order, nkb=8
    int i = blockIdx.x * 256 + threadIdx.x;     // 65536
    int b = i >> 7, k = i & 127;
    x0f[foff(b, k, 8)] = (f16)tgt[(size_t)b * 16384 + k];
}

__global__ void k_wihf(const float* __restrict__ Wih, f16* __restrict__ Wihf)
{   // W_ih in B-frag order, gate-interleaved rows, nkb=8
    int i = blockIdx.x * 256 + threadIdx.x;     // 1048576
    int rho = i >> 7, k = i & 127;
    int gate = rho & 3, hid = rho >> 2;
    Wihf[foff(rho, k, 8)] = (f16)Wih[((size_t)gate * 2048 + hid) * 128 + k];
}

__global__ void k_wihaf(const float* __restrict__ Wih, f16* __restrict__ Wihaf)
{   // W_ih in A-frag order (for k_wcomb), nkb=8
    int i = blockIdx.x * 256 + threadIdx.x;     // 1048576
    int r = i >> 7, k = i & 127;
    Wihaf[foff(r, k, 8)] = (f16)Wih[(size_t)r * 128 + k];
}

__global__ void k_woutTf(const float* __restrict__ Wout, f16* __restrict__ WoutTf)
{   // Wout^T (2048x128) in B-frag order (for k_wcomb), nkb=8
    int i = blockIdx.x * 256 + threadIdx.x;     // 262144
    int d = i >> 11, n = i & 2047;
    WoutTf[foff(n, d, 8)] = (f16)Wout[(size_t)d * 2048 + n];
}

__global__ void k_woutf(const float* __restrict__ Wout, f16* __restrict__ Woutf)
{   // Wout (128x2048) in B-frag order (for k_out), nkb=128
    int i = blockIdx.x * 256 + threadIdx.x;     // 262144
    int d = i >> 11, k = i & 2047;
    Woutf[foff(d, k, 128)] = (f16)Wout[(size_t)d * 2048 + k];
}

__global__ void k_bias(const float* __restrict__ bih, const float* __restrict__ bhh,
                       const float* __restrict__ Wih, const float* __restrict__ bout,
                       float* __restrict__ b0, float* __restrict__ bp)
{
    int r = blockIdx.x * 256 + threadIdx.x;
    if (r >= 8192) return;
    float s = bih[r] + bhh[r];
    float a = 0.f;
    for (int d = 0; d < 128; ++d) a += Wih[(size_t)r * 128 + d] * bout[d];
    b0[r] = s;        // step-0 bias
    bp[r] = s + a;    // recurrent bias (absorbs W_ih @ b_out)
}

// ---------------------------------------------------------------------------

extern "C" void kernel_launch(void* const* d_in, const int* in_sizes, int n_in,
                              void* d_out, int out_size, void* d_ws, size_t ws_size,
                              hipStream_t stream)
{
    const float* tgt  = (const float*)d_in[0];
    const float* Wih  = (const float*)d_in[1];
    const float* Whh  = (const float*)d_in[2];
    const float* bih  = (const float*)d_in[3];
    const float* bhh  = (const float*)d_in[4];
    const float* Wout = (const float*)d_in[5];
    const float* bout = (const float*)d_in[6];
    float* out = (float*)d_out;

    char* ws = (char*)d_ws;
    size_t off = 0;
    auto alloc = [&](size_t bytes) -> void* {
        void* p = ws + off;
        off += (bytes + 255) & ~(size_t)255;
        return p;
    };
    f16*   Wf     = (f16*)alloc((size_t)8192 * 2048 * 2);  // W' frag-order
    f16*   Wihf   = (f16*)alloc((size_t)8192 * 128 * 2);
    f16*   Wihaf  = (f16*)alloc((size_t)8192 * 128 * 2);
    f16*   WoutTf = (f16*)alloc((size_t)2048 * 128 * 2);
    f16*   Woutf  = (f16*)alloc((size_t)128 * 2048 * 2);
    f16*   x0f    = (f16*)alloc((size_t)512 * 128 * 2);
    float* b0     = (float*)alloc(8192 * 4);
    float* bp     = (float*)alloc(8192 * 4);
    float* Cst    = (float*)alloc((size_t)512 * 2048 * 4);

    const size_t slotsz = (size_t)512 * 2048;  // elements per h snapshot
    int depth = 0;
    const int cands[7] = {128, 64, 32, 16, 8, 4, 2};
    for (int i = 0; i < 7; ++i)
        if (off + (size_t)cands[i] * slotsz * 2 <= ws_size) { depth = cands[i]; break; }
    if (depth == 0) return;
    f16* Hbuf = (f16*)alloc((size_t)depth * slotsz * 2);
    const int rgshift = __builtin_ctz((unsigned)(depth * 4));

    hipMemsetAsync(Cst, 0, (size_t)512 * 2048 * 4, stream);
    k_x0f   <<<dim3(256),  dim3(256), 0, stream>>>(tgt, x0f);
    k_wihf  <<<dim3(4096), dim3(256), 0, stream>>>(Wih, Wihf);
    k_wihaf <<<dim3(4096), dim3(256), 0, stream>>>(Wih, Wihaf);
    k_woutTf<<<dim3(1024), dim3(256), 0, stream>>>(Wout, WoutTf);
    k_woutf <<<dim3(1024), dim3(256), 0, stream>>>(Wout, Woutf);
    k_bias  <<<dim3(32),   dim3(256), 0, stream>>>(bih, bhh, Wih, bout, b0, bp);
    k_wcomb <<<dim3(2048), dim3(256), 0, stream>>>(Wihaf, WoutTf, Whh, Wf);

    // step 0: gates = x0 @ W_ih^T + (b_ih+b_hh)  -> h^1 in slot 0
    k_step<<<dim3(512), dim3(256), 0, stream>>>(x0f, 8, Wihf, b0, Cst, Hbuf);
    // steps 1..127: gates = h @ W'^T + b'
    for (int s = 1; s < 128; ++s) {
        if ((s % depth) == 0)
            k_out<<<dim3(8 * depth), dim3(256), 0, stream>>>(
                Hbuf, Woutf, bout, out, s - depth, rgshift);
        k_step<<<dim3(512), dim3(256), 0, stream>>>(
            Hbuf + (size_t)((s - 1) % depth) * slotsz, 128, Wf, bp,
            Cst, Hbuf + (size_t)(s % depth) * slotsz);
    }
    k_out<<<dim3(8 * depth), dim3(256), 0, stream>>>(
        Hbuf, Woutf, bout, out, 128 - depth, rgshift);
}

// Round 8
// 4407.812 us; speedup vs baseline: 1.5774x; 1.0296x over previous
//
#include <hip/hip_runtime.h>
#include <hip/hip_fp16.h>

typedef _Float16 f16;
typedef __attribute__((ext_vector_type(8))) _Float16 f16x8;
typedef __attribute__((ext_vector_type(16))) float f32x16;

#define GLL(src, dst) __builtin_amdgcn_global_load_lds( \
    (const __attribute__((address_space(1))) void*)(src), \
    (__attribute__((address_space(3))) void*)(dst), 16, 0, 0)
#define SB0() __builtin_amdgcn_sched_barrier(0)

// Fragment-order storage (verified R5/R6): tensor[r,k] -> chunk
// (r>>5)*nkb + (k>>4); 512-elem 1KB chunk holds lane*8+e with
// r = base + (lane&31), k = kchunk*16 + (lane>>5)*8 + e.  One chunk == one
// mfma_32x32x16 A/B fragment for a 32-row block: a single contiguous 1KB
// wave read.
__device__ __forceinline__ size_t foff(int r, int k, int nkb) {
    return ((size_t)((r >> 5) * nkb + (k >> 4)) << 9)
         + (size_t)(((((k >> 3) & 1)) << 8) + ((r & 31) << 3) + (k & 7));
}

// ---------------------------------------------------------------------------
// Register GEMM core: block = 256 threads = 4 waves, each wave owns a
// PRIVATE 32-row stripe x all 64 block cols (wave-tile 32x64, acc[2]).
// A: direct global->register (frag-order, no LDS).  B: shared -> LDS via
// global_load_lds (linear image), read as contiguous ds_read_b128.
//
// DEPTH-4 pipeline, ONE barrier per STEP (R6 post-mortem: depth-2 exposed
// ~full VMEM latency; 2 barriers/STEP around 64cyc of MFMA):
//   STEP(t): wait vmcnt(N) [counted ledger below] -> s_barrier [acquire:
//   tile t staged by all waves; also proves all finished STEP(t-1) reads]
//   -> issue BG(t+3) into buf((t+3)&3) [== buf((t-1)&3), free by the same
//   barrier] -> ds_read tile t frags -> lgkmcnt(0)+sched_barrier (rule #18)
//   -> MFMA -> issue LA(t+4) into this R-set (WAR after MFMA reads).
// Issue ledger (per-thread vmcnt units; LA=4, BG=2, order pinned by SB0):
//   steady outstanding newer than tile t = LA(t+1..t+3)+BG(t+1,t+2) = 16;
//   tails r=2 ->12, r=1 ->6, r=0 ->0.  Issue->wait distance ~3 STEPs.
// Grid 512 x 256thr = 2 blocks/CU = 2 waves/SIMD for cross-block hiding.
// ---------------------------------------------------------------------------
__device__ __forceinline__ void rgemm(
    const f16* __restrict__ pA,              // wave A stripe base + lane*8
    const f16* __restrict__ pB0, const f16* __restrict__ pB1,
    f16* sB, int wv, int lane, int n, f32x16 acc[2])
{
    #pragma unroll
    for (int nt = 0; nt < 2; ++nt)
      #pragma unroll
      for (int e = 0; e < 16; ++e)
        acc[nt][e] = 0.f;

    // wave's staging assignment: col-group wv>>1, k-chunk pair jb = (wv&1)*2
    const f16* pBs = (wv >> 1) ? pB1 : pB0;
    const int jb = (wv & 1) * 2;
    f16* dst0 = sB + (wv >> 1) * 2048 + jb * 512;   // + buf*4096

    f16x8 R0[4], R1[4], R2[4], R3[4];
    auto LA = [&](f16x8 (&R)[4], int t) {           // 4 A-frag loads (K-64)
        size_t o = (size_t)t * 2048;
        R[0] = *(const f16x8*)(pA + o);
        R[1] = *(const f16x8*)(pA + o + 512);
        R[2] = *(const f16x8*)(pA + o + 1024);
        R[3] = *(const f16x8*)(pA + o + 1536);
    };
    auto BG = [&](int buf, int t) {                 // 2 GLL per wave
        size_t o = (size_t)t * 2048 + (size_t)jb * 512;
        GLL(pBs + o,       dst0 + buf * 4096);
        GLL(pBs + o + 512, dst0 + buf * 4096 + 512);
    };
    auto STEP = [&](f16x8 (&R)[4], int buf, int t) {
        const int r = n - 1 - t;                    // uniform
        if (r >= 3)      asm volatile("s_waitcnt vmcnt(16)" ::: "memory");
        else if (r == 2) asm volatile("s_waitcnt vmcnt(12)" ::: "memory");
        else if (r == 1) asm volatile("s_waitcnt vmcnt(6)"  ::: "memory");
        else             asm volatile("s_waitcnt vmcnt(0)"  ::: "memory");
        SB0();
        __builtin_amdgcn_s_barrier();               // acquire tile t
        SB0();
        if (t + 3 < n) BG((t + 3) & 3, t + 3);      // refill freed buffer
        SB0();
        f16x8 bf[2][4];
        const f16* bb = sB + buf * 4096 + lane * 8;
        #pragma unroll
        for (int nt = 0; nt < 2; ++nt)
          #pragma unroll
          for (int kk = 0; kk < 4; ++kk)
            bf[nt][kk] = *(const f16x8*)(bb + nt * 2048 + kk * 512);
        asm volatile("s_waitcnt lgkmcnt(0)" ::: "memory");
        SB0();                                      // rule #18 fence
        __builtin_amdgcn_s_setprio(1);
        #pragma unroll
        for (int kk = 0; kk < 4; ++kk)
          #pragma unroll
          for (int nt = 0; nt < 2; ++nt)
            acc[nt] = __builtin_amdgcn_mfma_f32_32x32x16_f16(
                R[kk], bf[nt][kk], acc[nt], 0, 0, 0);
        __builtin_amdgcn_s_setprio(0);
        SB0();
        if (t + 4 < n) LA(R, t + 4);                // WAR: after MFMA reads
        SB0();
    };

    // prologue: tiles 0..2 staged (B) / 0..3 loaded (A), order pinned
    SB0();
    BG(0, 0); LA(R0, 0);
    SB0();
    if (1 < n) { BG(1, 1); LA(R1, 1); }
    SB0();
    if (2 < n) { BG(2, 2); LA(R2, 2); }
    SB0();
    if (3 < n) LA(R3, 3);
    SB0();
    for (int t = 0; t < n; t += 4) {
        STEP(R0, 0, t);
        if (t + 1 < n) STEP(R1, 1, t + 1);
        if (t + 2 < n) STEP(R2, 2, t + 2);
        if (t + 3 < n) STEP(R3, 3, t + 3);
    }
}

#define PICKV(ii) ((ii) == 0 ? w0[e] : (ii) == 1 ? w1[e] : (ii) == 2 ? w2[e] : w3[e])

// ---------------------------------------------------------------------------
// Recurrent step: gates = A @ W^T + bias ; cell ; h out (frag-order), c f32.
// W gate-interleaved (rho = hid*4 + gate): a lane-quad holds the 4 gates of
// one hid -> 3x shfl_xor gather, no LDS exchange (verified R5/R6).
// Block = 128 batch rows x 64 gate-cols; grid 512 = 128 cg x 4 rg.
// ---------------------------------------------------------------------------
__global__ __launch_bounds__(256, 2) void k_step(
    const f16* __restrict__ Af, int nkb,
    const f16* __restrict__ Bf,
    const float* __restrict__ bias,
    float* __restrict__ Cst,
    f16* __restrict__ Hout)
{
    __shared__ alignas(16) f16 sB[16384];           // 4 x 8KB
    const int P = blockIdx.x;
    const int L = (P & 7) * ((int)gridDim.x >> 3) + (P >> 3);  // XCD swizzle
    const int cg = L >> 2, rg = L & 3;              // cg-major per XCD:
    const int tid = threadIdx.x;                    // W' panel L2-resident
    const int wv = tid >> 6, lane = tid & 63;
    const int l31 = lane & 31, hi = lane >> 5;
    const int mb = rg * 4 + wv;                     // 32-row A stripe
    const f16* pA  = Af + ((size_t)mb * nkb) * 512 + lane * 8;
    const f16* pB0 = Bf + ((size_t)(cg * 2) * nkb) * 512 + lane * 8;
    const f16* pB1 = pB0 + (size_t)nkb * 512;
    f32x16 acc[2];
    rgemm(pA, pB0, pB1, sB, wv, lane, nkb >> 2, acc);

    const int g = l31 & 3;                          // this lane's gate
    #pragma unroll
    for (int nt = 0; nt < 2; ++nt) {
        const int hid = cg * 16 + nt * 8 + (l31 >> 2);
        const float bown = bias[(g << 11) + hid];
        float w0[16], w1[16], w2[16], w3[16];
        #pragma unroll
        for (int e = 0; e < 16; ++e) {              // own-gate nonlinearity
            float x = acc[nt][e] + bown;
            float xx = (g == 2) ? 2.f * x : x;
            float s = 1.f / (1.f + __expf(-xx));
            w0[e] = (g == 2) ? 2.f * s - 1.f : s;   // tanh = 2*sig(2x)-1
        }
        #pragma unroll
        for (int e = 0; e < 16; ++e) {              // quad gather
            w1[e] = __shfl_xor(w0[e], 1);
            w2[e] = __shfl_xor(w0[e], 2);
            w3[e] = __shfl_xor(w0[e], 3);
        }
        const int rowb = rg * 128 + wv * 32 + 4 * hi;
        #pragma unroll
        for (int eg = 0; eg < 4; ++eg) {
            if (g == eg) {                          // static indices inside
                #pragma unroll
                for (int q = 0; q < 4; ++q) {
                    const int e = eg * 4 + q;
                    const float iv = PICKV(eg ^ 0);
                    const float fv = PICKV(eg ^ 1);
                    const float gv = PICKV(eg ^ 2);
                    const float ov = PICKV(eg ^ 3);
                    const int row = rowb + q + 8 * eg;
                    const size_t cidx = (size_t)row * 2048 + hid;
                    const float c = fv * Cst[cidx] + iv * gv;
                    Cst[cidx] = c;
                    Hout[foff(row, hid, 128)] = (f16)(ov * tanhf(c));
                }
            }
        }
    }
}

// out[b, t0+slot, d] = H @ W_out^T + b_out over M = depth*512 rows
__global__ __launch_bounds__(256, 2) void k_out(
    const f16* __restrict__ Hbase, const f16* __restrict__ Bf,
    const float* __restrict__ bout, float* __restrict__ out,
    int t0, int rgshift)
{
    __shared__ alignas(16) f16 sB[16384];
    const int P = blockIdx.x;
    const int L = (P & 7) * ((int)gridDim.x >> 3) + (P >> 3);
    const int cg = L >> rgshift;                    // 0..1
    const int rg = L & ((1 << rgshift) - 1);        // 0..depth*4-1
    const int tid = threadIdx.x;
    const int wv = tid >> 6, lane = tid & 63;
    const int l31 = lane & 31, hi = lane >> 5;
    const int m0 = rg * 128 + wv * 32;              // wave row stripe
    const int slot = m0 >> 9, mloc32 = (m0 & 511) >> 5;
    const f16* pA  = Hbase + (size_t)slot * 1048576
                   + ((size_t)mloc32 * 128) * 512 + lane * 8;
    const f16* pB0 = Bf + ((size_t)(cg * 2) * 128) * 512 + lane * 8;
    const f16* pB1 = pB0 + (size_t)128 * 512;
    f32x16 acc[2];
    rgemm(pA, pB0, pB1, sB, wv, lane, 32, acc);

    #pragma unroll
    for (int nt = 0; nt < 2; ++nt) {
        const int d = cg * 64 + nt * 32 + l31;
        const float bo = bout[d];
        #pragma unroll
        for (int e = 0; e < 16; ++e) {
            const int m = m0 + (e & 3) + 8 * (e >> 2) + 4 * hi;
            out[(size_t)(m & 511) * 16384 + (size_t)(t0 + (m >> 9)) * 128 + d]
                = acc[nt][e] + bo;
        }
    }
}

// Wc[r,k] = Whh[r,k] + Wih[r,:] @ Wout[:,k]; writes gate-interleaved frag-order
__global__ __launch_bounds__(256, 2) void k_wcomb(
    const f16* __restrict__ Af,   // Wihaf  (8192x128 A-frag order, nkb=8)
    const f16* __restrict__ Bf,   // WoutTf (2048x128 B-frag order, nkb=8)
    const float* __restrict__ Whh, f16* __restrict__ Wf)
{
    __shared__ alignas(16) f16 sB[16384];
    const int P = blockIdx.x;
    const int L = (P & 7) * ((int)gridDim.x >> 3) + (P >> 3);
    const int cg = L >> 6, rg = L & 63;             // 32 cg x 64 rg
    const int tid = threadIdx.x;
    const int wv = tid >> 6, lane = tid & 63;
    const int l31 = lane & 31, hi = lane >> 5;
    const int mb = rg * 4 + wv;
    const f16* pA  = Af + ((size_t)mb * 8) * 512 + lane * 8;
    const f16* pB0 = Bf + ((size_t)(cg * 2) * 8) * 512 + lane * 8;
    const f16* pB1 = pB0 + (size_t)8 * 512;
    f32x16 acc[2];
    rgemm(pA, pB0, pB1, sB, wv, lane, 2, acc);

    #pragma unroll
    for (int nt = 0; nt < 2; ++nt) {
        const int kc = cg * 64 + nt * 32 + l31;
        #pragma unroll
        for (int e = 0; e < 16; ++e) {
            const int r = rg * 128 + wv * 32 + (e & 3) + 8 * (e >> 2) + 4 * hi;
            const float v = acc[nt][e] + Whh[(size_t)r * 2048 + kc];
            const int rho = ((r & 2047) << 2) | (r >> 11);  // hid*4 + gate
            Wf[foff(rho, kc, 128)] = (f16)v;
        }
    }
}

// ---------------- prep kernels (once per launch, elementwise) ---------------

__global__ void k_x0f(const float* __restrict__ tgt, f16* __restrict__ x0f)
{   // x0 in A-frag order, nkb=8
    int i = blockIdx.x * 256 + threadIdx.x;     // 65536
    int b = i >> 7, k = i & 127;
    x0f[foff(b, k, 8)] = (f16)tgt[(size_t)b * 16384 + k];
}

__global__ void k_wihf(const float* __restrict__ Wih, f16* __restrict__ Wihf)
{   // W_ih in B-frag order, gate-interleaved rows, nkb=8
    int i = blockIdx.x * 256 + threadIdx.x;     // 1048576
    int rho = i >> 7, k = i & 127;
    int gate = rho & 3, hid = rho >> 2;
    Wihf[foff(rho, k, 8)] = (f16)Wih[((size_t)gate * 2048 + hid) * 128 + k];
}

__global__ void k_wihaf(const float* __restrict__ Wih, f16* __restrict__ Wihaf)
{   // W_ih in A-frag order (for k_wcomb), nkb=8
    int i = blockIdx.x * 256 + threadIdx.x;     // 1048576
    int r = i >> 7, k = i & 127;
    Wihaf[foff(r, k, 8)] = (f16)Wih[(size_t)r * 128 + k];
}

__global__ void k_woutTf(const float* __restrict__ Wout, f16* __restrict__ WoutTf)
{   // Wout^T (2048x128) in B-frag order (for k_wcomb), nkb=8
    int i = blockIdx.x * 256 + threadIdx.x;     // 262144
    int d = i >> 11, n = i & 2047;
    WoutTf[foff(n, d, 8)] = (f16)Wout[(size_t)d * 2048 + n];
}

__global__ void k_woutf(const float* __restrict__ Wout, f16* __restrict__ Woutf)
{   // Wout (128x2048) in B-frag order (for k_out), nkb=128
    int i = blockIdx.x * 256 + threadIdx.x;     // 262144
    int d = i >> 11, k = i & 2047;
    Woutf[foff(d, k, 128)] = (f16)Wout[(size_t)d * 2048 + k];
}

__global__ void k_bias(const float* __restrict__ bih, const float* __restrict__ bhh,
                       const float* __restrict__ Wih, const float* __restrict__ bout,
                       float* __restrict__ b0, float* __restrict__ bp)
{
    int r = blockIdx.x * 256 + threadIdx.x;
    if (r >= 8192) return;
    float s = bih[r] + bhh[r];
    float a = 0.f;
    for (int d = 0; d < 128; ++d) a += Wih[(size_t)r * 128 + d] * bout[d];
    b0[r] = s;        // step-0 bias
    bp[r] = s + a;    // recurrent bias (absorbs W_ih @ b_out)
}

// ---------------------------------------------------------------------------

extern "C" void kernel_launch(void* const* d_in, const int* in_sizes, int n_in,
                              void* d_out, int out_size, void* d_ws, size_t ws_size,
                              hipStream_t stream)
{
    const float* tgt  = (const float*)d_in[0];
    const float* Wih  = (const float*)d_in[1];
    const float* Whh  = (const float*)d_in[2];
    const float* bih  = (const float*)d_in[3];
    const float* bhh  = (const float*)d_in[4];
    const float* Wout = (const float*)d_in[5];
    const float* bout = (const float*)d_in[6];
    float* out = (float*)d_out;

    char* ws = (char*)d_ws;
    size_t off = 0;
    auto alloc = [&](size_t bytes) -> void* {
        void* p = ws + off;
        off += (bytes + 255) & ~(size_t)255;
        return p;
    };
    f16*   Wf     = (f16*)alloc((size_t)8192 * 2048 * 2);  // W' frag-order
    f16*   Wihf   = (f16*)alloc((size_t)8192 * 128 * 2);
    f16*   Wihaf  = (f16*)alloc((size_t)8192 * 128 * 2);
    f16*   WoutTf = (f16*)alloc((size_t)2048 * 128 * 2);
    f16*   Woutf  = (f16*)alloc((size_t)128 * 2048 * 2);
    f16*   x0f    = (f16*)alloc((size_t)512 * 128 * 2);
    float* b0     = (float*)alloc(8192 * 4);
    float* bp     = (float*)alloc(8192 * 4);
    float* Cst    = (float*)alloc((size_t)512 * 2048 * 4);

    const size_t slotsz = (size_t)512 * 2048;  // elements per h snapshot
    int depth = 0;
    const int cands[7] = {128, 64, 32, 16, 8, 4, 2};
    for (int i = 0; i < 7; ++i)
        if (off + (size_t)cands[i] * slotsz * 2 <= ws_size) { depth = cands[i]; break; }
    if (depth == 0) return;
    f16* Hbuf = (f16*)alloc((size_t)depth * slotsz * 2);
    const int rgshift = __builtin_ctz((unsigned)(depth * 4));

    hipMemsetAsync(Cst, 0, (size_t)512 * 2048 * 4, stream);
    k_x0f   <<<dim3(256),  dim3(256), 0, stream>>>(tgt, x0f);
    k_wihf  <<<dim3(4096), dim3(256), 0, stream>>>(Wih, Wihf);
    k_wihaf <<<dim3(4096), dim3(256), 0, stream>>>(Wih, Wihaf);
    k_woutTf<<<dim3(1024), dim3(256), 0, stream>>>(Wout, WoutTf);
    k_woutf <<<dim3(1024), dim3(256), 0, stream>>>(Wout, Woutf);
    k_bias  <<<dim3(32),   dim3(256), 0, stream>>>(bih, bhh, Wih, bout, b0, bp);
    k_wcomb <<<dim3(2048), dim3(256), 0, stream>>>(Wihaf, WoutTf, Whh, Wf);

    // step 0: gates = x0 @ W_ih^T + (b_ih+b_hh)  -> h^1 in slot 0
    k_step<<<dim3(512), dim3(256), 0, stream>>>(x0f, 8, Wihf, b0, Cst, Hbuf);
    // steps 1..127: gates = h @ W'^T + b'
    for (int s = 1; s < 128; ++s) {
        if ((s % depth) == 0)
            k_out<<<dim3(8 * depth), dim3(256), 0, stream>>>(
                Hbuf, Woutf, bout, out, s - depth, rgshift);
        k_step<<<dim3(512), dim3(256), 0, stream>>>(
            Hbuf + (size_t)((s - 1) % depth) * slotsz, 128, Wf, bp,
            Cst, Hbuf + (size_t)(s % depth) * slotsz);
    }
    k_out<<<dim3(8 * depth), dim3(256), 0, stream>>>(
        Hbuf, Woutf, bout, out, 128 - depth, rgshift);
}